// Round 16
// baseline (46.333 us; speedup 1.0000x reference)
//
#include <hip/hip_runtime.h>
#include <hip/hip_bf16.h>

typedef __attribute__((ext_vector_type(8))) short bf16x8;
typedef __attribute__((ext_vector_type(4))) float f32x4;
typedef __attribute__((ext_vector_type(4))) float vf4;
typedef __attribute__((ext_vector_type(2))) float vf2;

static __device__ __forceinline__ unsigned short f2bf(float f) {
    unsigned int u = __float_as_uint(f);
    unsigned int rnd = 0x7FFFu + ((u >> 16) & 1u);
    return (unsigned short)((u + rnd) >> 16);
}

// pack two f32 -> 2xbf16 (RNE) using v_cvt_pk_bf16_f32
static __device__ __forceinline__ bf16x8 cvt8(float4 u, float4 v) {
    union { bf16x8 r; __hip_bfloat162 h[4]; } o;
    o.h[0] = __float22bfloat162_rn(float2{u.x, u.y});
    o.h[1] = __float22bfloat162_rn(float2{u.z, u.w});
    o.h[2] = __float22bfloat162_rn(float2{v.x, v.y});
    o.h[3] = __float22bfloat162_rn(float2{v.z, v.w});
    return o.r;
}

// nontemporal float4 load (nt bit: no L2 allocate - for read-once streams)
static __device__ __forceinline__ float4 ntload4(const float* p) {
    vf4 v = __builtin_nontemporal_load((const vf4*)p);
    return float4{v.x, v.y, v.z, v.w};
}

// ---------------- Kernel 1: hypernetwork hw = hyper@W1+b1, bias = hyper@Wb+bb
__global__ __launch_bounds__(256)
void hypernet_kernel(const float* __restrict__ hyper,   // (8,256)
                     const float* __restrict__ W1,      // (256,4096)
                     const float* __restrict__ b1,      // (4096)
                     const float* __restrict__ Wb,      // (256,64)
                     const float* __restrict__ bb,      // (64)
                     float* __restrict__ hw,            // ws: 8*4096
                     float* __restrict__ bias)          // ws: 8*64
{
    __shared__ float red[256];
    const int tid = threadIdx.x;
    const int p   = tid >> 5;          // 0..7  (d-range)
    const int jj  = tid & 31;          // 0..31 (output within block)
    const int o0  = blockIdx.x * 32;
    const int o   = o0 + jj;

    float acc = 0.f;
    if (o0 < 8 * 4096) {               // hw part (uniform per block)
        int h = o >> 12, j = o & 4095;
        const float* hr = hyper + (h << 8);
        #pragma unroll
        for (int i = 0; i < 32; ++i) {
            int d = (p << 5) + i;
            acc += hr[d] * W1[d * 4096 + j];
        }
    } else {                           // bias part
        int t = o - 8 * 4096;          // 0..511
        int h = t >> 6, s = t & 63;
        const float* hr = hyper + (h << 8);
        #pragma unroll
        for (int i = 0; i < 32; ++i) {
            int d = (p << 5) + i;
            acc += hr[d] * Wb[d * 64 + s];
        }
    }
    red[tid] = acc;
    __syncthreads();
    if (p == 0) {
        float sum = red[jj]       + red[32 + jj]  + red[64 + jj]  + red[96 + jj]
                  + red[128 + jj] + red[160 + jj] + red[192 + jj] + red[224 + jj];
        if (o0 < 8 * 4096) hw[o] = sum + b1[o & 4095];
        else {
            int t = o - 8 * 4096;
            bias[t] = sum + bb[t & 63];
        }
    }
}

// ---------------- Kernel 2: W[h] = down@up, packed directly into MFMA
// B-fragment order for v_mfma_f32_16x16x32_bf16 (validated in round 1).
__global__ void pack_kernel(const float* __restrict__ hw,          // 8*4096
                            unsigned short* __restrict__ packed)   // 32768 bf16
{
    int p = blockIdx.x * blockDim.x + threadIdx.x;  // 0..32767
    int b   = p & 7;
    int l   = (p >> 3) & 63;
    int kap = (p >> 9) & 1;
    int n   = p >> 10;                              // 0..31
    int k   = kap * 32 + ((l >> 4) << 3) + b;       // 0..63 (= target feature d)
    int col = (n << 4) + (l & 15);                  // 0..511
    int h = col >> 6, s = col & 63;
    const float* hwh = hw + h * 4096;
    float acc = 0.f;
    #pragma unroll
    for (int r = 0; r < 32; ++r)
        acc += hwh[k * 32 + r] * hwh[2048 + r * 64 + s];
    packed[p] = f2bf(acc);
}

// ---------------- Kernel 3: main — round-14 structure (NT stores, 35.2us)
// + NT loads for the read-once X/Mask streams (protect packedB's L2
// residency) + X tile-0 prefetch issued FIRST (longest dep chain starts
// earliest). 2048 blocks x 64 rows, TPW=4, (256,3), masks in LDS broadcast,
// dist-1 X prefetch, bias in epilogue.
#define TPW 4   // row-tiles per wave; block covers 64 rows

__global__ __launch_bounds__(256, 3)
void main_kernel(const float* __restrict__ X,       // (M,64)
                 const float* __restrict__ Mask,    // (M,8)
                 const unsigned short* __restrict__ packedB,
                 const float* __restrict__ bias,    // (8,64)
                 float* __restrict__ Out)           // (M,64)
{
    __shared__ float sM[16 * TPW * 8];  // 2 KB: 64 rows x 8 masks

    const int tid  = threadIdx.x;
    const int lane = tid & 63;
    const int w    = tid >> 6;          // wave id 0..3 -> output col tile
    const int c    = lane & 15;         // A row-within-tile / D col-within-tile
    const int g    = lane >> 4;         // k-group / D row-group
    const int rowBase = blockIdx.x * (16 * TPW);
    const int s = (w << 4) + c;         // output column 0..63

    // lane reads X row (rowBase + t*16 + c), cols [g*8,g*8+8) and [32+g*8, ...)
    const float* xrow = X + (long)(rowBase + c) * 64 + (g << 3);

    // ---- X tile-0 prefetch FIRST: longest dependency chain starts earliest
    float4 px0 = ntload4(xrow);
    float4 px1 = ntload4(xrow + 4);
    float4 px2 = ntload4(xrow + 32);
    float4 px3 = ntload4(xrow + 36);

    // ---- stage mask tile to LDS: 512 floats = 256 vf2 (coalesced, NT)
    {
        vf2 mv = __builtin_nontemporal_load((const vf2*)(Mask + (long)rowBase * 8) + tid);
        sM[tid * 2]     = mv.x;
        sM[tid * 2 + 1] = mv.y;
    }

    // ---- B fragments for this wave (L2-hot 64KB buffer - keep cached)
    bf16x8 Bf[8][2];
    #pragma unroll
    for (int h = 0; h < 8; ++h) {
        const unsigned short* pb = packedB + ((((h * 4 + w) * 2) * 64) + lane) * 8;
        Bf[h][0] = *(const bf16x8*)pb;
        Bf[h][1] = *(const bf16x8*)(pb + 512);
    }

    // ---- bias for this lane's output column
    float biasr[8];
    #pragma unroll
    for (int h = 0; h < 8; ++h) biasr[h] = bias[h * 64 + s];

    __syncthreads();

    #pragma unroll 2
    for (int t = 0; t < TPW; ++t) {
        float4 cx0 = px0, cx1 = px1, cx2 = px2, cx3 = px3;

        // prefetch X for tile t+1 (NT: read-once stream)
        if (t + 1 < TPW) {
            const float* xp = xrow + (t + 1) * 1024;
            px0 = ntload4(xp);
            px1 = ntload4(xp + 4);
            px2 = ntload4(xp + 32);
            px3 = ntload4(xp + 36);
        }

        bf16x8 a0 = cvt8(cx0, cx1);     // cols [g*8, g*8+8)
        bf16x8 a1 = cvt8(cx2, cx3);     // cols [32+g*8, 32+g*8+8)

        f32x4 acc[8];
        #pragma unroll
        for (int h = 0; h < 8; ++h) acc[h] = (f32x4)(0.f);
        #pragma unroll
        for (int h = 0; h < 8; ++h) {
            acc[h] = __builtin_amdgcn_mfma_f32_16x16x32_bf16(a0, Bf[h][0], acc[h], 0, 0, 0);
            acc[h] = __builtin_amdgcn_mfma_f32_16x16x32_bf16(a1, Bf[h][1], acc[h], 0, 0, 0);
        }

        // epilogue: out[row,s] = sum_h m[row,h] * (Z + bias)
        // masks via LDS broadcast (16 lanes share each address)
        #pragma unroll
        for (int i = 0; i < 4; ++i) {
            const int r = t * 16 + (g << 2) + i;
            const float4 ml = *(const float4*)(&sM[r * 8]);
            const float4 mh = *(const float4*)(&sM[r * 8 + 4]);
            float o = ml.x * (acc[0][i] + biasr[0]);
            o = fmaf(ml.y, acc[1][i] + biasr[1], o);
            o = fmaf(ml.z, acc[2][i] + biasr[2], o);
            o = fmaf(ml.w, acc[3][i] + biasr[3], o);
            o = fmaf(mh.x, acc[4][i] + biasr[4], o);
            o = fmaf(mh.y, acc[5][i] + biasr[5], o);
            o = fmaf(mh.z, acc[6][i] + biasr[6], o);
            o = fmaf(mh.w, acc[7][i] + biasr[7], o);
            __builtin_nontemporal_store(o, &Out[(long)(rowBase + r) * 64 + s]);
        }
    }
}

extern "C" void kernel_launch(void* const* d_in, const int* in_sizes, int n_in,
                              void* d_out, int out_size, void* d_ws, size_t ws_size,
                              hipStream_t stream) {
    const float* target = (const float*)d_in[0];   // (B,L,64)
    const float* hyper  = (const float*)d_in[1];   // (8,256)
    const float* mask   = (const float*)d_in[2];   // (B,L,8)
    const float* W1     = (const float*)d_in[3];   // (256,4096)
    const float* b1     = (const float*)d_in[4];   // (4096)
    const float* Wb     = (const float*)d_in[5];   // (256,64)
    const float* bb     = (const float*)d_in[6];   // (64)
    float* out = (float*)d_out;

    float* hw   = (float*)d_ws;                         // 32768 f32
    float* bias = hw + 8 * 4096;                        // 512 f32
    unsigned short* packed = (unsigned short*)(bias + 512); // 32768 bf16

    const int M = in_sizes[0] / 64;                     // 131072 rows

    hipLaunchKernelGGL(hypernet_kernel, dim3((8 * 4096 + 8 * 64) / 32), dim3(256),
                       0, stream, hyper, W1, b1, Wb, bb, hw, bias);
    hipLaunchKernelGGL(pack_kernel, dim3(512), dim3(64), 0, stream, hw, packed);
    hipLaunchKernelGGL(main_kernel, dim3(M / (16 * TPW)), dim3(256), 0, stream,
                       target, mask, packed, bias, out);
}

// Round 17
// 38.168 us; speedup vs baseline: 1.2139x; 1.2139x over previous
//
#include <hip/hip_runtime.h>
#include <hip/hip_bf16.h>

typedef __attribute__((ext_vector_type(8))) short bf16x8;
typedef __attribute__((ext_vector_type(4))) float f32x4;
typedef __attribute__((ext_vector_type(2))) float vf2;

static __device__ __forceinline__ unsigned short f2bf(float f) {
    unsigned int u = __float_as_uint(f);
    unsigned int rnd = 0x7FFFu + ((u >> 16) & 1u);
    return (unsigned short)((u + rnd) >> 16);
}

// pack two f32 -> 2xbf16 (RNE) using v_cvt_pk_bf16_f32
static __device__ __forceinline__ bf16x8 cvt8(float4 u, float4 v) {
    union { bf16x8 r; __hip_bfloat162 h[4]; } o;
    o.h[0] = __float22bfloat162_rn(float2{u.x, u.y});
    o.h[1] = __float22bfloat162_rn(float2{u.z, u.w});
    o.h[2] = __float22bfloat162_rn(float2{v.x, v.y});
    o.h[3] = __float22bfloat162_rn(float2{v.z, v.w});
    return o.r;
}

// ---------------- Kernel 1: hypernetwork hw = hyper@W1+b1, bias = hyper@Wb+bb
__global__ __launch_bounds__(256)
void hypernet_kernel(const float* __restrict__ hyper,   // (8,256)
                     const float* __restrict__ W1,      // (256,4096)
                     const float* __restrict__ b1,      // (4096)
                     const float* __restrict__ Wb,      // (256,64)
                     const float* __restrict__ bb,      // (64)
                     float* __restrict__ hw,            // ws: 8*4096
                     float* __restrict__ bias)          // ws: 8*64
{
    __shared__ float red[256];
    const int tid = threadIdx.x;
    const int p   = tid >> 5;          // 0..7  (d-range)
    const int jj  = tid & 31;          // 0..31 (output within block)
    const int o0  = blockIdx.x * 32;
    const int o   = o0 + jj;

    float acc = 0.f;
    if (o0 < 8 * 4096) {               // hw part (uniform per block)
        int h = o >> 12, j = o & 4095;
        const float* hr = hyper + (h << 8);
        #pragma unroll
        for (int i = 0; i < 32; ++i) {
            int d = (p << 5) + i;
            acc += hr[d] * W1[d * 4096 + j];
        }
    } else {                           // bias part
        int t = o - 8 * 4096;          // 0..511
        int h = t >> 6, s = t & 63;
        const float* hr = hyper + (h << 8);
        #pragma unroll
        for (int i = 0; i < 32; ++i) {
            int d = (p << 5) + i;
            acc += hr[d] * Wb[d * 64 + s];
        }
    }
    red[tid] = acc;
    __syncthreads();
    if (p == 0) {
        float sum = red[jj]       + red[32 + jj]  + red[64 + jj]  + red[96 + jj]
                  + red[128 + jj] + red[160 + jj] + red[192 + jj] + red[224 + jj];
        if (o0 < 8 * 4096) hw[o] = sum + b1[o & 4095];
        else {
            int t = o - 8 * 4096;
            bias[t] = sum + bb[t & 63];
        }
    }
}

// ---------------- Kernel 2: W[h] = down@up, packed directly into MFMA
// B-fragment order for v_mfma_f32_16x16x32_bf16 (validated in round 1).
__global__ void pack_kernel(const float* __restrict__ hw,          // 8*4096
                            unsigned short* __restrict__ packed)   // 32768 bf16
{
    int p = blockIdx.x * blockDim.x + threadIdx.x;  // 0..32767
    int b   = p & 7;
    int l   = (p >> 3) & 63;
    int kap = (p >> 9) & 1;
    int n   = p >> 10;                              // 0..31
    int k   = kap * 32 + ((l >> 4) << 3) + b;       // 0..63 (= target feature d)
    int col = (n << 4) + (l & 15);                  // 0..511
    int h = col >> 6, s = col & 63;
    const float* hwh = hw + h * 4096;
    float acc = 0.f;
    #pragma unroll
    for (int r = 0; r < 32; ++r)
        acc += hwh[k * 32 + r] * hwh[2048 + r * 64 + s];
    packed[p] = f2bf(acc);
}

// ---------------- Kernel 3: main — round-14 base (NT stores, 35.2us best).
// Single A/B variable this round: Mask staging load is NT (true zero-reuse
// stream). X loads stay CACHED — all 4 waves read the same X rows, so L1/L2
// reuse is real (round 16: NT X loads cost -31%).
#define TPW 4   // row-tiles per wave; block covers 64 rows

__global__ __launch_bounds__(256, 3)
void main_kernel(const float* __restrict__ X,       // (M,64)
                 const float* __restrict__ Mask,    // (M,8)
                 const unsigned short* __restrict__ packedB,
                 const float* __restrict__ bias,    // (8,64)
                 float* __restrict__ Out)           // (M,64)
{
    __shared__ float sM[16 * TPW * 8];  // 2 KB: 64 rows x 8 masks

    const int tid  = threadIdx.x;
    const int lane = tid & 63;
    const int w    = tid >> 6;          // wave id 0..3 -> output col tile
    const int c    = lane & 15;         // A row-within-tile / D col-within-tile
    const int g    = lane >> 4;         // k-group / D row-group
    const int rowBase = blockIdx.x * (16 * TPW);
    const int s = (w << 4) + c;         // output column 0..63

    // ---- stage mask tile to LDS: 512 floats = 256 vf2 (coalesced, NT)
    {
        vf2 mv = __builtin_nontemporal_load((const vf2*)(Mask + (long)rowBase * 8) + tid);
        sM[tid * 2]     = mv.x;
        sM[tid * 2 + 1] = mv.y;
    }

    // ---- B fragments for this wave (L2-hot 64KB buffer)
    bf16x8 Bf[8][2];
    #pragma unroll
    for (int h = 0; h < 8; ++h) {
        const unsigned short* pb = packedB + ((((h * 4 + w) * 2) * 64) + lane) * 8;
        Bf[h][0] = *(const bf16x8*)pb;
        Bf[h][1] = *(const bf16x8*)(pb + 512);
    }

    // ---- bias for this lane's output column
    float biasr[8];
    #pragma unroll
    for (int h = 0; h < 8; ++h) biasr[h] = bias[h * 64 + s];

    // lane reads X row (rowBase + t*16 + c), cols [g*8,g*8+8) and [32+g*8, ...)
    const float* xrow = X + (long)(rowBase + c) * 64 + (g << 3);

    // ---- prologue: prefetch tile 0 (cached: 4 waves share these lines)
    float4 px0 = *(const float4*)(xrow);
    float4 px1 = *(const float4*)(xrow + 4);
    float4 px2 = *(const float4*)(xrow + 32);
    float4 px3 = *(const float4*)(xrow + 36);

    __syncthreads();

    #pragma unroll 2
    for (int t = 0; t < TPW; ++t) {
        float4 cx0 = px0, cx1 = px1, cx2 = px2, cx3 = px3;

        // prefetch X for tile t+1
        if (t + 1 < TPW) {
            const float* xp = xrow + (t + 1) * 1024;
            px0 = *(const float4*)(xp);
            px1 = *(const float4*)(xp + 4);
            px2 = *(const float4*)(xp + 32);
            px3 = *(const float4*)(xp + 36);
        }

        bf16x8 a0 = cvt8(cx0, cx1);     // cols [g*8, g*8+8)
        bf16x8 a1 = cvt8(cx2, cx3);     // cols [32+g*8, 32+g*8+8)

        f32x4 acc[8];
        #pragma unroll
        for (int h = 0; h < 8; ++h) acc[h] = (f32x4)(0.f);
        #pragma unroll
        for (int h = 0; h < 8; ++h) {
            acc[h] = __builtin_amdgcn_mfma_f32_16x16x32_bf16(a0, Bf[h][0], acc[h], 0, 0, 0);
            acc[h] = __builtin_amdgcn_mfma_f32_16x16x32_bf16(a1, Bf[h][1], acc[h], 0, 0, 0);
        }

        // epilogue: out[row,s] = sum_h m[row,h] * (Z + bias)
        // masks via LDS broadcast (16 lanes share each address)
        #pragma unroll
        for (int i = 0; i < 4; ++i) {
            const int r = t * 16 + (g << 2) + i;
            const float4 ml = *(const float4*)(&sM[r * 8]);
            const float4 mh = *(const float4*)(&sM[r * 8 + 4]);
            float o = ml.x * (acc[0][i] + biasr[0]);
            o = fmaf(ml.y, acc[1][i] + biasr[1], o);
            o = fmaf(ml.z, acc[2][i] + biasr[2], o);
            o = fmaf(ml.w, acc[3][i] + biasr[3], o);
            o = fmaf(mh.x, acc[4][i] + biasr[4], o);
            o = fmaf(mh.y, acc[5][i] + biasr[5], o);
            o = fmaf(mh.z, acc[6][i] + biasr[6], o);
            o = fmaf(mh.w, acc[7][i] + biasr[7], o);
            __builtin_nontemporal_store(o, &Out[(long)(rowBase + r) * 64 + s]);
        }
    }
}

extern "C" void kernel_launch(void* const* d_in, const int* in_sizes, int n_in,
                              void* d_out, int out_size, void* d_ws, size_t ws_size,
                              hipStream_t stream) {
    const float* target = (const float*)d_in[0];   // (B,L,64)
    const float* hyper  = (const float*)d_in[1];   // (8,256)
    const float* mask   = (const float*)d_in[2];   // (B,L,8)
    const float* W1     = (const float*)d_in[3];   // (256,4096)
    const float* b1     = (const float*)d_in[4];   // (4096)
    const float* Wb     = (const float*)d_in[5];   // (256,64)
    const float* bb     = (const float*)d_in[6];   // (64)
    float* out = (float*)d_out;

    float* hw   = (float*)d_ws;                         // 32768 f32
    float* bias = hw + 8 * 4096;                        // 512 f32
    unsigned short* packed = (unsigned short*)(bias + 512); // 32768 bf16

    const int M = in_sizes[0] / 64;                     // 131072 rows

    hipLaunchKernelGGL(hypernet_kernel, dim3((8 * 4096 + 8 * 64) / 32), dim3(256),
                       0, stream, hyper, W1, b1, Wb, bb, hw, bias);
    hipLaunchKernelGGL(pack_kernel, dim3(512), dim3(64), 0, stream, hw, packed);
    hipLaunchKernelGGL(main_kernel, dim3(M / (16 * TPW)), dim3(256), 0, stream,
                       target, mask, packed, bias, out);
}

// Round 18
// 34.985 us; speedup vs baseline: 1.3244x; 1.0910x over previous
//
#include <hip/hip_runtime.h>
#include <hip/hip_bf16.h>

typedef __attribute__((ext_vector_type(8))) short bf16x8;
typedef __attribute__((ext_vector_type(4))) float f32x4;

static __device__ __forceinline__ unsigned short f2bf(float f) {
    unsigned int u = __float_as_uint(f);
    unsigned int rnd = 0x7FFFu + ((u >> 16) & 1u);
    return (unsigned short)((u + rnd) >> 16);
}

// pack two f32 -> 2xbf16 (RNE) using v_cvt_pk_bf16_f32
static __device__ __forceinline__ bf16x8 cvt8(float4 u, float4 v) {
    union { bf16x8 r; __hip_bfloat162 h[4]; } o;
    o.h[0] = __float22bfloat162_rn(float2{u.x, u.y});
    o.h[1] = __float22bfloat162_rn(float2{u.z, u.w});
    o.h[2] = __float22bfloat162_rn(float2{v.x, v.y});
    o.h[3] = __float22bfloat162_rn(float2{v.z, v.w});
    return o.r;
}

// ---------------- Kernel 1: hypernetwork hw = hyper@W1+b1, bias = hyper@Wb+bb
__global__ __launch_bounds__(256)
void hypernet_kernel(const float* __restrict__ hyper,   // (8,256)
                     const float* __restrict__ W1,      // (256,4096)
                     const float* __restrict__ b1,      // (4096)
                     const float* __restrict__ Wb,      // (256,64)
                     const float* __restrict__ bb,      // (64)
                     float* __restrict__ hw,            // ws: 8*4096
                     float* __restrict__ bias)          // ws: 8*64
{
    __shared__ float red[256];
    const int tid = threadIdx.x;
    const int p   = tid >> 5;          // 0..7  (d-range)
    const int jj  = tid & 31;          // 0..31 (output within block)
    const int o0  = blockIdx.x * 32;
    const int o   = o0 + jj;

    float acc = 0.f;
    if (o0 < 8 * 4096) {               // hw part (uniform per block)
        int h = o >> 12, j = o & 4095;
        const float* hr = hyper + (h << 8);
        #pragma unroll
        for (int i = 0; i < 32; ++i) {
            int d = (p << 5) + i;
            acc += hr[d] * W1[d * 4096 + j];
        }
    } else {                           // bias part
        int t = o - 8 * 4096;          // 0..511
        int h = t >> 6, s = t & 63;
        const float* hr = hyper + (h << 8);
        #pragma unroll
        for (int i = 0; i < 32; ++i) {
            int d = (p << 5) + i;
            acc += hr[d] * Wb[d * 64 + s];
        }
    }
    red[tid] = acc;
    __syncthreads();
    if (p == 0) {
        float sum = red[jj]       + red[32 + jj]  + red[64 + jj]  + red[96 + jj]
                  + red[128 + jj] + red[160 + jj] + red[192 + jj] + red[224 + jj];
        if (o0 < 8 * 4096) hw[o] = sum + b1[o & 4095];
        else {
            int t = o - 8 * 4096;
            bias[t] = sum + bb[t & 63];
        }
    }
}

// ---------------- Kernel 2: W[h] = down@up, packed directly into MFMA
// B-fragment order for v_mfma_f32_16x16x32_bf16 (validated in round 1).
__global__ void pack_kernel(const float* __restrict__ hw,          // 8*4096
                            unsigned short* __restrict__ packed)   // 32768 bf16
{
    int p = blockIdx.x * blockDim.x + threadIdx.x;  // 0..32767
    int b   = p & 7;
    int l   = (p >> 3) & 63;
    int kap = (p >> 9) & 1;
    int n   = p >> 10;                              // 0..31
    int k   = kap * 32 + ((l >> 4) << 3) + b;       // 0..63 (= target feature d)
    int col = (n << 4) + (l & 15);                  // 0..511
    int h = col >> 6, s = col & 63;
    const float* hwh = hw + h * 4096;
    float acc = 0.f;
    #pragma unroll
    for (int r = 0; r < 32; ++r)
        acc += hwh[k * 32 + r] * hwh[2048 + r * 64 + s];
    packed[p] = f2bf(acc);
}

// ---------------- Kernel 3: main — FINAL: round-14 exact (best measured,
// 35.2us). 2048 blocks x 64 rows, TPW=4, (256,3); masks in LDS broadcast
// (cached loads); dist-1 X prefetch (cached - 4 waves share lines); bias in
// epilogue; NONTEMPORAL stores (the one validated cache-policy win, +4%).
// Measured-and-rejected: NT loads (-8..31%), C-init bias refold (-8%),
// 8-wave blocks (-30%), LDS X staging (null), DMA staging (spill),
// dist-2 prefetch (null), persistent grid (-90%), occupancy forcing (spill).
#define TPW 4   // row-tiles per wave; block covers 64 rows

__global__ __launch_bounds__(256, 3)
void main_kernel(const float* __restrict__ X,       // (M,64)
                 const float* __restrict__ Mask,    // (M,8)
                 const unsigned short* __restrict__ packedB,
                 const float* __restrict__ bias,    // (8,64)
                 float* __restrict__ Out)           // (M,64)
{
    __shared__ float sM[16 * TPW * 8];  // 2 KB: 64 rows x 8 masks

    const int tid  = threadIdx.x;
    const int lane = tid & 63;
    const int w    = tid >> 6;          // wave id 0..3 -> output col tile
    const int c    = lane & 15;         // A row-within-tile / D col-within-tile
    const int g    = lane >> 4;         // k-group / D row-group
    const int rowBase = blockIdx.x * (16 * TPW);
    const int s = (w << 4) + c;         // output column 0..63

    // ---- stage mask tile to LDS: 512 floats = 256 float2 (coalesced)
    {
        const float2* Mv = (const float2*)(Mask + (long)rowBase * 8);
        ((float2*)sM)[tid] = Mv[tid];
    }

    // ---- B fragments for this wave (L2-hot 64KB buffer)
    bf16x8 Bf[8][2];
    #pragma unroll
    for (int h = 0; h < 8; ++h) {
        const unsigned short* pb = packedB + ((((h * 4 + w) * 2) * 64) + lane) * 8;
        Bf[h][0] = *(const bf16x8*)pb;
        Bf[h][1] = *(const bf16x8*)(pb + 512);
    }

    // ---- bias for this lane's output column
    float biasr[8];
    #pragma unroll
    for (int h = 0; h < 8; ++h) biasr[h] = bias[h * 64 + s];

    // lane reads X row (rowBase + t*16 + c), cols [g*8,g*8+8) and [32+g*8, ...)
    const float* xrow = X + (long)(rowBase + c) * 64 + (g << 3);

    // ---- prologue: prefetch tile 0 (cached: 4 waves share these lines)
    float4 px0 = *(const float4*)(xrow);
    float4 px1 = *(const float4*)(xrow + 4);
    float4 px2 = *(const float4*)(xrow + 32);
    float4 px3 = *(const float4*)(xrow + 36);

    __syncthreads();

    #pragma unroll 2
    for (int t = 0; t < TPW; ++t) {
        float4 cx0 = px0, cx1 = px1, cx2 = px2, cx3 = px3;

        // prefetch X for tile t+1
        if (t + 1 < TPW) {
            const float* xp = xrow + (t + 1) * 1024;
            px0 = *(const float4*)(xp);
            px1 = *(const float4*)(xp + 4);
            px2 = *(const float4*)(xp + 32);
            px3 = *(const float4*)(xp + 36);
        }

        bf16x8 a0 = cvt8(cx0, cx1);     // cols [g*8, g*8+8)
        bf16x8 a1 = cvt8(cx2, cx3);     // cols [32+g*8, 32+g*8+8)

        f32x4 acc[8];
        #pragma unroll
        for (int h = 0; h < 8; ++h) acc[h] = (f32x4)(0.f);
        #pragma unroll
        for (int h = 0; h < 8; ++h) {
            acc[h] = __builtin_amdgcn_mfma_f32_16x16x32_bf16(a0, Bf[h][0], acc[h], 0, 0, 0);
            acc[h] = __builtin_amdgcn_mfma_f32_16x16x32_bf16(a1, Bf[h][1], acc[h], 0, 0, 0);
        }

        // epilogue: out[row,s] = sum_h m[row,h] * (Z + bias)
        // masks via LDS broadcast (16 lanes share each address)
        #pragma unroll
        for (int i = 0; i < 4; ++i) {
            const int r = t * 16 + (g << 2) + i;
            const float4 ml = *(const float4*)(&sM[r * 8]);
            const float4 mh = *(const float4*)(&sM[r * 8 + 4]);
            float o = ml.x * (acc[0][i] + biasr[0]);
            o = fmaf(ml.y, acc[1][i] + biasr[1], o);
            o = fmaf(ml.z, acc[2][i] + biasr[2], o);
            o = fmaf(ml.w, acc[3][i] + biasr[3], o);
            o = fmaf(mh.x, acc[4][i] + biasr[4], o);
            o = fmaf(mh.y, acc[5][i] + biasr[5], o);
            o = fmaf(mh.z, acc[6][i] + biasr[6], o);
            o = fmaf(mh.w, acc[7][i] + biasr[7], o);
            __builtin_nontemporal_store(o, &Out[(long)(rowBase + r) * 64 + s]);
        }
    }
}

extern "C" void kernel_launch(void* const* d_in, const int* in_sizes, int n_in,
                              void* d_out, int out_size, void* d_ws, size_t ws_size,
                              hipStream_t stream) {
    const float* target = (const float*)d_in[0];   // (B,L,64)
    const float* hyper  = (const float*)d_in[1];   // (8,256)
    const float* mask   = (const float*)d_in[2];   // (B,L,8)
    const float* W1     = (const float*)d_in[3];   // (256,4096)
    const float* b1     = (const float*)d_in[4];   // (4096)
    const float* Wb     = (const float*)d_in[5];   // (256,64)
    const float* bb     = (const float*)d_in[6];   // (64)
    float* out = (float*)d_out;

    float* hw   = (float*)d_ws;                         // 32768 f32
    float* bias = hw + 8 * 4096;                        // 512 f32
    unsigned short* packed = (unsigned short*)(bias + 512); // 32768 bf16

    const int M = in_sizes[0] / 64;                     // 131072 rows

    hipLaunchKernelGGL(hypernet_kernel, dim3((8 * 4096 + 8 * 64) / 32), dim3(256),
                       0, stream, hyper, W1, b1, Wb, bb, hw, bias);
    hipLaunchKernelGGL(pack_kernel, dim3(512), dim3(64), 0, stream, hw, packed);
    hipLaunchKernelGGL(main_kernel, dim3(M / (16 * TPW)), dim3(256), 0, stream,
                       target, mask, packed, bias, out);
}